// Round 5
// baseline (724.346 us; speedup 1.0000x reference)
//
#include <hip/hip_runtime.h>
#include <hip/hip_bf16.h>
#include <cstddef>

#define PI_F 3.14159265358979323846f

// ---------------------------------------------------------------------------
// Module-global device scratch; fully rewritten each launch before being read.
// ---------------------------------------------------------------------------
#define IMG (512 * 512)
__device__ float2 g_buf0[5 * IMG];     // 10.5 MB
__device__ float2 g_buf1[5 * IMG];     // 10.5 MB
__device__ float2 g_kernT[25 * IMG];   // 52.4 MB, transposed kernel cache
__device__ int    g_isbf16;            // input-dtype flag, set by k_detect

// Dual-dtype input load: bf16 (flag=1) or fp32 (flag=0).
__device__ inline float ldin(const void* p, size_t i, int isb) {
    if (isb) return __bfloat162float(((const __hip_bfloat16*)p)[i]);
    return ((const float*)p)[i];
}

// ---------------------------------------------------------------------------
// Input dtype detector (kept as a zero-cost hedge; round-3/4 differential
// already showed inputs are fp32: identical absmax with and without it).
// ---------------------------------------------------------------------------
__global__ void k_detect(const unsigned short* __restrict__ u) {
    if (threadIdx.x == 0 && blockIdx.x == 0) {
        int insane = 0;
        for (int i = 0; i < 2048; ++i) {
            unsigned int b = ((unsigned int)u[i]) << 16;
            float v = __uint_as_float(b);
            float a = fabsf(v);
            if (!(a == 0.0f || (a > 1e-8f && a < 1e8f))) insane++;  // NaN -> insane
        }
        g_isbf16 = (insane == 0) ? 1 : 0;
    }
}

// ---------------------------------------------------------------------------
// 512-point complex FFT in LDS, Stockham radix-2, 128 threads/row.
// DIR=-1 forward (numpy sign), +1 inverse (unnormalized IDFT sum).
// Hand-verified at N=4/N=8 against the DFT definition.
// ---------------------------------------------------------------------------
template<int DIR>
__device__ float2* fft512_lds(float2* sA, float2* sB, int t) {
    float2* src = sA;
    float2* dst = sB;
    int Ns = 1;
    #pragma unroll
    for (int stage = 0; stage < 9; ++stage) {
        __syncthreads();
        #pragma unroll
        for (int q = 0; q < 2; ++q) {
            int j  = t + q * 128;
            float2 v0 = src[j];
            float2 v1 = src[j + 256];
            int m = j & (Ns - 1);
            float ang = (float)DIR * PI_F * (float)m / (float)Ns;
            float sv, cv;
            __sincosf(ang, &sv, &cv);
            float2 tw = make_float2(v1.x * cv - v1.y * sv,
                                    v1.x * sv + v1.y * cv);
            int idxD = ((j & ~(Ns - 1)) << 1) | m;
            dst[idxD]      = make_float2(v0.x + tw.x, v0.y + tw.y);
            dst[idxD + Ns] = make_float2(v0.x - tw.x, v0.y - tw.y);
        }
        float2* tmp = src; src = dst; dst = tmp;
        Ns <<= 1;
    }
    __syncthreads();
    return src;
}

// ---------------------------------------------------------------------------
// Stage 1: centered pad (256->512) + coil modulate (mps_c * x) + row FFT
// along x. One block per (a, y). Zero rows skip the FFT entirely.
// ---------------------------------------------------------------------------
__global__ void k_fft1(const void* __restrict__ xr, const void* __restrict__ xi,
                       const void* __restrict__ mr, const void* __restrict__ mi,
                       int coil) {
    int row = blockIdx.x;            // a*512 + y
    int a = row >> 9;
    int y = row & 511;
    int t = threadIdx.x;
    float2* out = g_buf0 + (size_t)row * 512;

    __shared__ float2 sA[512];
    __shared__ float2 sB[512];

    if (y < 128 || y >= 384) {
        #pragma unroll
        for (int q = 0; q < 4; ++q) out[t + q * 128] = make_float2(0.f, 0.f);
        return;
    }
    int isb = g_isbf16;
    int ym = y - 128;
    #pragma unroll
    for (int q = 0; q < 4; ++q) {
        int x5 = t + q * 128;
        float2 v = make_float2(0.f, 0.f);
        if (x5 >= 128 && x5 < 384) {
            int xm = x5 - 128;
            size_t xIdx = ((size_t)a * 256 + ym) * 256 + xm;
            size_t mIdx = ((size_t)coil * 256 + ym) * 256 + xm;
            float ar = ldin(xr, xIdx, isb), ai = ldin(xi, xIdx, isb);
            float br = ldin(mr, mIdx, isb), bi = ldin(mi, mIdx, isb);
            v = make_float2(ar * br - ai * bi, ar * bi + ai * br);
        }
        sA[x5] = v;
    }
    float2* res = fft512_lds<-1>(sA, sB, t);
    #pragma unroll
    for (int q = 0; q < 4; ++q) out[t + q * 128] = res[t + q * 128];
}

// ---------------------------------------------------------------------------
// Row-wise forward FFT over g_buf1 in place.
// ---------------------------------------------------------------------------
__global__ void k_fft_rows_fwd() {
    int row = blockIdx.x;
    int t = threadIdx.x;
    float2* s = g_buf1 + (size_t)row * 512;
    __shared__ float2 sA[512];
    __shared__ float2 sB[512];
    #pragma unroll
    for (int q = 0; q < 4; ++q) sA[t + q * 128] = s[t + q * 128];
    float2* res = fft512_lds<-1>(sA, sB, t);
    #pragma unroll
    for (int q = 0; q < 4; ++q) s[t + q * 128] = res[t + q * 128];
}

// ---------------------------------------------------------------------------
// Tiled transpose g_buf0 -> g_buf1 per image: buf1[a][r][c] = buf0[a][c][r],
// r in [rowBase, rowBase + 32*gridDim.y).
// ---------------------------------------------------------------------------
__global__ void k_transpose(int rowBase) {
    __shared__ float2 tile[32][33];
    int a = blockIdx.z;
    const float2* s = g_buf0 + ((size_t)a << 18);
    float2* d = g_buf1 + ((size_t)a << 18);
    int c0 = blockIdx.x * 32;
    int r0 = rowBase + blockIdx.y * 32;
    int tx = threadIdx.x, ty = threadIdx.y;
    for (int i = ty; i < 32; i += 8)
        tile[i][tx] = s[(size_t)(c0 + i) * 512 + (r0 + tx)];
    __syncthreads();
    for (int i = ty; i < 32; i += 8)
        d[(size_t)(r0 + i) * 512 + (c0 + tx)] = tile[tx][i];
}

// ---------------------------------------------------------------------------
// Build transposed interleaved kernel cache:
// g_kernT[m][kx*512+ky] = kern[m][ky*512+kx], m = aout*5+ain.
// ---------------------------------------------------------------------------
__global__ void k_kernT(const void* __restrict__ kr, const void* __restrict__ ki) {
    __shared__ float2 tile[32][33];
    int m = blockIdx.z;
    size_t base = (size_t)m << 18;
    int c0 = blockIdx.x * 32;
    int r0 = blockIdx.y * 32;
    int tx = threadIdx.x, ty = threadIdx.y;
    int isb = g_isbf16;
    for (int i = ty; i < 32; i += 8) {
        size_t idx = base + (size_t)(c0 + i) * 512 + (r0 + tx);
        tile[i][tx] = make_float2(ldin(kr, idx, isb), ldin(ki, idx, isb));
    }
    __syncthreads();
    for (int i = ty; i < 32; i += 8)
        g_kernT[base + (size_t)(r0 + i) * 512 + (c0 + tx)] = tile[tx][i];
}

// ---------------------------------------------------------------------------
// K-space mix (sum over ain, scaled) fused with row IFFT over ky.
// One block per (aout, kx). Reads g_buf1 (Fx^T), writes g_buf0[aout][kx][y].
// ---------------------------------------------------------------------------
__global__ void k_ifft1(float scale) {
    int blk = blockIdx.x;            // aout*512 + kx
    int aout = blk >> 9;
    int kx = blk & 511;
    int t = threadIdx.x;
    __shared__ float2 sA[512];
    __shared__ float2 sB[512];
    #pragma unroll
    for (int q = 0; q < 4; ++q) {
        int ky = t + q * 128;
        float2 acc = make_float2(0.f, 0.f);
        #pragma unroll
        for (int ain = 0; ain < 5; ++ain) {
            float2 kv = g_kernT[(((size_t)(aout * 5 + ain)) << 18) + ((size_t)kx << 9) + ky];
            float2 fv = g_buf1[(((size_t)ain) << 18) + ((size_t)kx << 9) + ky];
            acc.x += kv.x * fv.x - kv.y * fv.y;
            acc.y += kv.x * fv.y + kv.y * fv.x;
        }
        sA[ky] = make_float2(acc.x * scale, acc.y * scale);
    }
    float2* res = fft512_lds<1>(sA, sB, t);
    float2* out = g_buf0 + (size_t)blk * 512;
    #pragma unroll
    for (int q = 0; q < 4; ++q) out[t + q * 128] = res[t + q * 128];
}

// ---------------------------------------------------------------------------
// Final row IFFT (over kx) + centered crop + conj(mps) multiply + accumulate.
// OUTPUT LAYOUT: PLANAR — full Re plane [A,H,W] at offset 0, full Im plane
// at offset A*H*W (matches the generator's complex->_r/_i split convention
// seen on the inputs). Round 3/4 used interleaved and failed with the
// uncorrelated-values signature (0.318 ~ 4.75*sigma*sqrt(2)).
// first=1 (coil 0) writes; others accumulate. Bounds-guarded.
// ---------------------------------------------------------------------------
__global__ void k_ifft2(const void* __restrict__ mr, const void* __restrict__ mi,
                        int coil, int first, float* __restrict__ out, int outFloats) {
    int blk = blockIdx.x;            // a*256 + h
    int a = blk >> 8;
    int h = blk & 255;
    int y = h + 128;
    int t = threadIdx.x;
    __shared__ float2 sA[512];
    __shared__ float2 sB[512];
    const float2* s = g_buf1 + ((size_t)a << 18) + ((size_t)y << 9);
    #pragma unroll
    for (int q = 0; q < 4; ++q) sA[t + q * 128] = s[t + q * 128];
    float2* res = fft512_lds<1>(sA, sB, t);
    int isb = g_isbf16;
    const size_t PLANE = (size_t)5 * 256 * 256;   // A*H*W = 327680
    #pragma unroll
    for (int q = 0; q < 2; ++q) {
        int w = t + q * 128;         // 0..255 output col
        float2 v = res[w + 128];
        size_t mIdx = ((size_t)coil * 256 + h) * 256 + w;
        float br = ldin(mr, mIdx, isb), bi = -ldin(mi, mIdx, isb);  // conj(mps)
        float orr = v.x * br - v.y * bi;
        float oi  = v.x * bi + v.y * br;
        size_t pIdx = ((size_t)a * 256 + h) * 256 + w;   // plane-local index
        size_t reIdx = pIdx;
        size_t imIdx = PLANE + pIdx;
        if (first) {
            if (reIdx < (size_t)outFloats) out[reIdx] = orr;
            if (imIdx < (size_t)outFloats) out[imIdx] = oi;
        } else {
            if (reIdx < (size_t)outFloats) out[reIdx] += orr;
            if (imIdx < (size_t)outFloats) out[imIdx] += oi;
        }
    }
}

// ---------------------------------------------------------------------------
extern "C" void kernel_launch(void* const* d_in, const int* in_sizes, int n_in,
                              void* d_out, int out_size, void* d_ws, size_t ws_size,
                              hipStream_t stream) {
    const void* xr = d_in[0];
    const void* xi = d_in[1];
    const void* mr = d_in[2];
    const void* mi = d_in[3];
    const void* kr = d_in[4];
    const void* ki = d_in[5];
    float* out = (float*)d_out;

    const int A = 5, C = 12;
    (void)d_ws; (void)ws_size; (void)n_in; (void)in_sizes;

    // No runtime API calls here (graph-capture safety). Coil 0 of k_ifft2
    // writes (not accumulates), so d_out needs no memset.

    k_detect<<<1, 64, 0, stream>>>((const unsigned short*)xr);
    k_kernT<<<dim3(16, 16, A * A), dim3(32, 8), 0, stream>>>(kr, ki);

    const float scale = 4.0f / 262144.0f;   // OVERSAMP^2 / (Hp*Wp), ortho norms

    for (int c = 0; c < C; ++c) {
        k_fft1<<<A * 512, 128, 0, stream>>>(xr, xi, mr, mi, c);
        k_transpose<<<dim3(16, 16, A), dim3(32, 8), 0, stream>>>(0);
        k_fft_rows_fwd<<<A * 512, 128, 0, stream>>>();
        k_ifft1<<<A * 512, 128, 0, stream>>>(scale);
        k_transpose<<<dim3(16, 8, A), dim3(32, 8), 0, stream>>>(128);
        k_ifft2<<<A * 256, 128, 0, stream>>>(mr, mi, c, (c == 0) ? 1 : 0,
                                             out, out_size);
    }
}

// Round 8
// 628.203 us; speedup vs baseline: 1.1530x; 1.1530x over previous
//
#include <hip/hip_runtime.h>
#include <cstddef>

#define PI_F 3.14159265358979323846f
#define A_ 5
#define C_ 12

// ---------------------------------------------------------------------------
// Device-global scratch, 73.4 MB total == round-5's proven-loadable footprint.
// All rewritten every launch before being read. Per-coil layouts:
//   g_bufA after k_fft1c  : [a][ym(256)][kx(512)]   (ym = padded y - 128)
//   g_bufB after k_transA : [a][kx(512)][ym(256)]
//   g_bufC after k_colfft : [a][kx(512)][ky(512)]
//   g_bufA after k_mixifft: [a][kx(512)][ym(256)]   (ym = result y - 128)
//   g_bufB after k_transB : [a][ym(256)][kx(512)]
// NO atomics to d_out and NO >10KB-LDS kernels: those are the two R6/R7
// novelties under crash suspicion (R7 falsified the BSS-size theory).
// ---------------------------------------------------------------------------
__device__ float2 g_bufA[A_ * 256 * 512];   //  5.24 MB
__device__ float2 g_bufB[A_ * 512 * 256];   //  5.24 MB
__device__ float2 g_bufC[A_ * 512 * 512];   // 10.49 MB
__device__ float2 g_kernT[25 * 512 * 512];  // 52.43 MB, transposed + pre-scaled

// ---------------------------------------------------------------------------
// Twiddle table: tab[k] = e^{-2 pi i k/512}, k in [0,256). Stage s needs
// e^{-i pi m/Ns} = tab[m << (8-s)].
// ---------------------------------------------------------------------------
__device__ inline void build_tab128(float2* tab, int t) {
    #pragma unroll
    for (int q = 0; q < 2; ++q) {
        int k = t + q * 128;
        float s, c;
        __sincosf(-2.0f * PI_F * (float)k / 512.0f, &s, &c);
        tab[k] = make_float2(c, s);
    }
}

// ---------------------------------------------------------------------------
// 512-pt Stockham radix-2 FFT in LDS, 128 threads, table twiddles.
// DIR=-1 forward (numpy sign), +1 inverse (unnormalized). Proven structure
// (round 5) with sincos replaced by the exact table.
// ---------------------------------------------------------------------------
template<int DIR>
__device__ float2* fft512_tab(float2* sA, float2* sB, const float2* tab, int t) {
    float2* src = sA;
    float2* dst = sB;
    #pragma unroll
    for (int stage = 0; stage < 9; ++stage) {
        int Ns = 1 << stage;
        __syncthreads();
        #pragma unroll
        for (int q = 0; q < 2; ++q) {
            int j = t + q * 128;
            float2 v0 = src[j];
            float2 v1 = src[j + 256];
            int m = j & (Ns - 1);
            float2 w = tab[m << (8 - stage)];
            float cv = w.x;
            float sv = (DIR < 0) ? w.y : -w.y;
            float2 tw = make_float2(v1.x * cv - v1.y * sv,
                                    v1.x * sv + v1.y * cv);
            int idxD = ((j & ~(Ns - 1)) << 1) | m;
            dst[idxD]      = make_float2(v0.x + tw.x, v0.y + tw.y);
            dst[idxD + Ns] = make_float2(v0.x - tw.x, v0.y - tw.y);
        }
        float2* tmp = src; src = dst; dst = tmp;
    }
    __syncthreads();
    return src;
}

// ---------------------------------------------------------------------------
// Transposed, pre-scaled kernel cache (round-5 k_kernT + scale fold):
// g_kernT[m][kx*512+ky] = scale * kern[m][ky*512+kx], m = aout*5+ain.
// ---------------------------------------------------------------------------
__global__ void k_kernT2(const float* __restrict__ kr, const float* __restrict__ ki,
                         float scale) {
    __shared__ float2 tile[32][33];
    int m = blockIdx.z;
    size_t base = (size_t)m << 18;
    int c0 = blockIdx.x * 32;
    int r0 = blockIdx.y * 32;
    int tx = threadIdx.x, ty = threadIdx.y;
    for (int i = ty; i < 32; i += 8) {
        size_t idx = base + (size_t)(c0 + i) * 512 + (r0 + tx);
        tile[i][tx] = make_float2(kr[idx] * scale, ki[idx] * scale);
    }
    __syncthreads();
    for (int i = ty; i < 32; i += 8)
        g_kernT[base + (size_t)(r0 + i) * 512 + (c0 + tx)] = tile[tx][i];
}

// ---------------------------------------------------------------------------
// Pad x + modulate mps_c*x + row FFT along x, banded store (nonzero rows
// only). Block = a*256 + ym, ym in [0,256) (padded y = ym + 128).
// ---------------------------------------------------------------------------
__global__ void k_fft1c(const float* __restrict__ xr, const float* __restrict__ xi,
                        const float* __restrict__ mr, const float* __restrict__ mi,
                        int coil) {
    int row = blockIdx.x;            // a*256 + ym
    int a = row >> 8;
    int ym = row & 255;
    int t = threadIdx.x;
    __shared__ float2 sA[512], sB[512], tab[256];
    build_tab128(tab, t);
    size_t xBase = ((size_t)a * 256 + ym) * 256;
    size_t mBase = ((size_t)coil * 256 + ym) * 256;
    #pragma unroll
    for (int q = 0; q < 4; ++q) {
        int x5 = t + q * 128;
        float2 v = make_float2(0.f, 0.f);
        if (x5 >= 128 && x5 < 384) {
            int xm = x5 - 128;
            float ar = xr[xBase + xm], ai = xi[xBase + xm];
            float br = mr[mBase + xm], bi = mi[mBase + xm];
            v = make_float2(ar * br - ai * bi, ar * bi + ai * br);
        }
        sA[x5] = v;
    }
    float2* res = fft512_tab<-1>(sA, sB, tab, t);
    float2* o = g_bufA + (size_t)row * 512;
    #pragma unroll
    for (int q = 0; q < 4; ++q) o[t + q * 128] = res[t + q * 128];
}

// ---------------------------------------------------------------------------
// transA: per-a transpose (256 ym x 512 kx) -> (512 kx x 256 ym).
// ---------------------------------------------------------------------------
__global__ void k_transA() {
    __shared__ float2 tile[32][33];
    int a = blockIdx.z;
    const float2* sIn = g_bufA + (size_t)a * (256 * 512);
    float2* sOut = g_bufB + (size_t)a * (512 * 256);
    int kx0 = blockIdx.x * 32, ym0 = blockIdx.y * 32;
    int tx = threadIdx.x, ty = threadIdx.y;
    for (int i = ty; i < 32; i += 8)
        tile[i][tx] = sIn[(size_t)(ym0 + i) * 512 + kx0 + tx];
    __syncthreads();
    for (int i = ty; i < 32; i += 8)
        sOut[(size_t)(kx0 + i) * 256 + ym0 + tx] = tile[tx][i];
}

// ---------------------------------------------------------------------------
// Column FFT with pad-on-load: block (a, kx); read the 256-band, place at
// padded y in [128,384), zero elsewhere, forward FFT, write 512 ky values.
// ---------------------------------------------------------------------------
__global__ void k_colfft() {
    int blk = blockIdx.x;            // a*512 + kx
    int t = threadIdx.x;
    __shared__ float2 sA[512], sB[512], tab[256];
    build_tab128(tab, t);
    const float2* grow = g_bufB + (size_t)blk * 256;
    #pragma unroll
    for (int q = 0; q < 4; ++q) {
        int y = t + q * 128;
        sA[y] = (y >= 128 && y < 384) ? grow[y - 128] : make_float2(0.f, 0.f);
    }
    float2* res = fft512_tab<-1>(sA, sB, tab, t);
    float2* o = g_bufC + (size_t)blk * 512;
    #pragma unroll
    for (int q = 0; q < 4; ++q) o[t + q * 128] = res[t + q * 128];
}

// ---------------------------------------------------------------------------
// K-space mix (sum over ain, kernT pre-scaled) + column IFFT over ky, banded
// store of the surviving center rows. Block (aout, kx). Clone of round-5's
// proven k_ifft1 with table twiddles + banded output.
// ---------------------------------------------------------------------------
__global__ void k_mixifft() {
    int blk = blockIdx.x;            // aout*512 + kx
    int aout = blk >> 9;
    int kx = blk & 511;
    int t = threadIdx.x;
    __shared__ float2 sA[512], sB[512], tab[256];
    build_tab128(tab, t);
    #pragma unroll
    for (int q = 0; q < 4; ++q) {
        int ky = t + q * 128;
        float2 acc = make_float2(0.f, 0.f);
        #pragma unroll
        for (int ain = 0; ain < A_; ++ain) {
            float2 kv = g_kernT[(((size_t)(aout * A_ + ain)) << 18) +
                                ((size_t)kx << 9) + ky];
            float2 fv = g_bufC[(((size_t)ain) << 18) + ((size_t)kx << 9) + ky];
            acc.x += kv.x * fv.x - kv.y * fv.y;
            acc.y += kv.x * fv.y + kv.y * fv.x;
        }
        sA[ky] = acc;
    }
    float2* res = fft512_tab<1>(sA, sB, tab, t);
    // keep y in [128,384) -> ym = y-128; store [aout][kx][ym]
    float2* o = g_bufA + (size_t)blk * 256;
    o[t]       = res[t + 128];       // y = t+128        -> ym = t
    o[t + 128] = res[t + 256];       // y = t+256 (<384) -> ym = t+128
}

// ---------------------------------------------------------------------------
// transB: per-a transpose (512 kx x 256 ym) -> (256 ym x 512 kx).
// ---------------------------------------------------------------------------
__global__ void k_transB() {
    __shared__ float2 tile[32][33];
    int a = blockIdx.z;
    const float2* sIn = g_bufA + (size_t)a * (512 * 256);
    float2* sOut = g_bufB + (size_t)a * (256 * 512);
    int ym0 = blockIdx.x * 32, kx0 = blockIdx.y * 32;
    int tx = threadIdx.x, ty = threadIdx.y;
    for (int i = ty; i < 32; i += 8)
        tile[i][tx] = sIn[(size_t)(kx0 + i) * 256 + ym0 + tx];
    __syncthreads();
    for (int i = ty; i < 32; i += 8)
        sOut[(size_t)(ym0 + i) * 512 + kx0 + tx] = tile[tx][i];
}

// ---------------------------------------------------------------------------
// Row IFFT along kx + crop x + conj(mps)*acc into PLANAR out (Re plane
// [5,256,256] then Im plane). first=1: write (covers all of d_out at coil 0);
// else read-add-write. NO atomics (R6/R7 crash suspect). Guarded like R5.
// ---------------------------------------------------------------------------
__global__ void k_out(const float* __restrict__ mr, const float* __restrict__ mi,
                      int coil, int first, float* __restrict__ out, int outFloats) {
    int row = blockIdx.x;            // a*256 + h
    int a = row >> 8;
    int h = row & 255;
    int t = threadIdx.x;
    __shared__ float2 sA[512], sB[512], tab[256];
    build_tab128(tab, t);
    const float2* s = g_bufB + (size_t)row * 512;
    #pragma unroll
    for (int q = 0; q < 4; ++q) sA[t + q * 128] = s[t + q * 128];
    float2* res = fft512_tab<1>(sA, sB, tab, t);
    #pragma unroll
    for (int q = 0; q < 2; ++q) {
        int w = t + q * 128;         // output col 0..255 (x = w+128)
        float2 v = res[w + 128];
        size_t mIdx = ((size_t)coil * 256 + h) * 256 + w;
        float br = mr[mIdx], bi = -mi[mIdx];   // conj(mps)
        float orr = v.x * br - v.y * bi;
        float oi  = v.x * bi + v.y * br;
        size_t p = ((size_t)a * 256 + h) * 256 + w;
        size_t reIdx = p, imIdx = 327680 + p;
        if (first) {
            if (reIdx < (size_t)outFloats) out[reIdx] = orr;
            if (imIdx < (size_t)outFloats) out[imIdx] = oi;
        } else {
            if (reIdx < (size_t)outFloats) out[reIdx] += orr;
            if (imIdx < (size_t)outFloats) out[imIdx] += oi;
        }
    }
}

// ---------------------------------------------------------------------------
extern "C" void kernel_launch(void* const* d_in, const int* in_sizes, int n_in,
                              void* d_out, int out_size, void* d_ws, size_t ws_size,
                              hipStream_t stream) {
    const float* xr = (const float*)d_in[0];
    const float* xi = (const float*)d_in[1];
    const float* mr = (const float*)d_in[2];
    const float* mi = (const float*)d_in[3];
    const float* kr = (const float*)d_in[4];
    const float* ki = (const float*)d_in[5];
    float* out = (float*)d_out;
    (void)d_ws; (void)ws_size; (void)n_in; (void)in_sizes;

    const float scale = 4.0f / 262144.0f;   // OVERSAMP^2/(Hp*Wp), ortho norms

    // No runtime API calls (graph-capture safety); coil 0 writes d_out fully.
    k_kernT2<<<dim3(16, 16, 25), dim3(32, 8), 0, stream>>>(kr, ki, scale);

    for (int c = 0; c < C_; ++c) {
        k_fft1c<<<A_ * 256, 128, 0, stream>>>(xr, xi, mr, mi, c);
        k_transA<<<dim3(16, 8, A_), dim3(32, 8), 0, stream>>>();
        k_colfft<<<A_ * 512, 128, 0, stream>>>();
        k_mixifft<<<A_ * 512, 128, 0, stream>>>();
        k_transB<<<dim3(8, 16, A_), dim3(32, 8), 0, stream>>>();
        k_out<<<A_ * 256, 128, 0, stream>>>(mr, mi, c, (c == 0) ? 1 : 0,
                                            out, out_size);
    }
}

// Round 9
// 444.434 us; speedup vs baseline: 1.6298x; 1.4135x over previous
//
#include <hip/hip_runtime.h>
#include <cstddef>

#define PI_F 3.14159265358979323846f
#define A_  5
#define C_  12
#define CPG 4            // coils per group
#define NG  3            // groups (CPG*NG == C_)
#define RPG (CPG * A_)   // (coil,a) rows per group = 20

// ---------------------------------------------------------------------------
// Device-global scratch, 136.4 MB. R7 showed the R6/R7 aborts reproduce at
// the proven 73.4 MB footprint (culprits: fused 42KB-LDS kernel / atomics to
// d_out — both absent here), so BSS size is not implicated. Per-group layouts:
//   g_bufA after k_fft1c  : [ca][ym(256)][kx(512)]   (ym = padded y - 128)
//   g_bufB after k_transA : [ca][kx(512)][ym(256)]
//   g_bufC after k_colfft : [ca][kx(512)][ky(512)]
//   g_bufA after k_mixifft: [ca][kx(512)][ym(256)]   (ym = result y - 128)
//   g_bufB after k_transB : [ca][ym(256)][kx(512)]
// ca = cl*A_ + a, cl in [0,CPG).
// ---------------------------------------------------------------------------
__device__ float2 g_bufA[RPG * 256 * 512];  // 21.0 MB
__device__ float2 g_bufB[RPG * 512 * 256];  // 21.0 MB
__device__ float2 g_bufC[RPG * 512 * 512];  // 41.9 MB
__device__ float2 g_kernT[25 * 512 * 512];  // 52.4 MB, transposed + pre-scaled

// ---------------------------------------------------------------------------
// Twiddle table: tab[k] = e^{-2 pi i k/512}, k in [0,256). Stage s needs
// e^{-i pi m/Ns} = tab[m << (8-s)].
// ---------------------------------------------------------------------------
__device__ inline void build_tab128(float2* tab, int t) {
    #pragma unroll
    for (int q = 0; q < 2; ++q) {
        int k = t + q * 128;
        float s, c;
        __sincosf(-2.0f * PI_F * (float)k / 512.0f, &s, &c);
        tab[k] = make_float2(c, s);
    }
}

// ---------------------------------------------------------------------------
// 512-pt Stockham radix-2 FFT in LDS, 128 threads, table twiddles.
// DIR=-1 forward (numpy sign), +1 inverse (unnormalized). Returns sB after
// the odd stage count; caller may overwrite sA immediately after res reads.
// ---------------------------------------------------------------------------
template<int DIR>
__device__ float2* fft512_tab(float2* sA, float2* sB, const float2* tab, int t) {
    float2* src = sA;
    float2* dst = sB;
    #pragma unroll
    for (int stage = 0; stage < 9; ++stage) {
        int Ns = 1 << stage;
        __syncthreads();
        #pragma unroll
        for (int q = 0; q < 2; ++q) {
            int j = t + q * 128;
            float2 v0 = src[j];
            float2 v1 = src[j + 256];
            int m = j & (Ns - 1);
            float2 w = tab[m << (8 - stage)];
            float cv = w.x;
            float sv = (DIR < 0) ? w.y : -w.y;
            float2 tw = make_float2(v1.x * cv - v1.y * sv,
                                    v1.x * sv + v1.y * cv);
            int idxD = ((j & ~(Ns - 1)) << 1) | m;
            dst[idxD]      = make_float2(v0.x + tw.x, v0.y + tw.y);
            dst[idxD + Ns] = make_float2(v0.x - tw.x, v0.y - tw.y);
        }
        float2* tmp = src; src = dst; dst = tmp;
    }
    __syncthreads();
    return src;
}

// ---------------------------------------------------------------------------
// Transposed, pre-scaled kernel cache:
// g_kernT[m][kx*512+ky] = scale * kern[m][ky*512+kx], m = aout*5+ain.
// ---------------------------------------------------------------------------
__global__ void k_kernT2(const float* __restrict__ kr, const float* __restrict__ ki,
                         float scale) {
    __shared__ float2 tile[32][33];
    int m = blockIdx.z;
    size_t base = (size_t)m << 18;
    int c0 = blockIdx.x * 32;
    int r0 = blockIdx.y * 32;
    int tx = threadIdx.x, ty = threadIdx.y;
    for (int i = ty; i < 32; i += 8) {
        size_t idx = base + (size_t)(c0 + i) * 512 + (r0 + tx);
        tile[i][tx] = make_float2(kr[idx] * scale, ki[idx] * scale);
    }
    __syncthreads();
    for (int i = ty; i < 32; i += 8)
        g_kernT[base + (size_t)(r0 + i) * 512 + (c0 + tx)] = tile[tx][i];
}

// ---------------------------------------------------------------------------
// Pad x + modulate mps_c*x + row FFT along x, banded store. One group of CPG
// coils per dispatch. Block = ca*256 + ym.
// ---------------------------------------------------------------------------
__global__ void k_fft1c(const float* __restrict__ xr, const float* __restrict__ xi,
                        const float* __restrict__ mr, const float* __restrict__ mi,
                        int coilBase) {
    int row = blockIdx.x;            // ca*256 + ym
    int ca = row >> 8;
    int ym = row & 255;
    int cl = ca / A_;
    int a = ca - cl * A_;
    int coil = coilBase + cl;
    int t = threadIdx.x;
    __shared__ float2 sA[512], sB[512], tab[256];
    build_tab128(tab, t);
    size_t xBase = ((size_t)a * 256 + ym) * 256;
    size_t mBase = ((size_t)coil * 256 + ym) * 256;
    #pragma unroll
    for (int q = 0; q < 4; ++q) {
        int x5 = t + q * 128;
        float2 v = make_float2(0.f, 0.f);
        if (x5 >= 128 && x5 < 384) {
            int xm = x5 - 128;
            float ar = xr[xBase + xm], ai = xi[xBase + xm];
            float br = mr[mBase + xm], bi = mi[mBase + xm];
            v = make_float2(ar * br - ai * bi, ar * bi + ai * br);
        }
        sA[x5] = v;
    }
    float2* res = fft512_tab<-1>(sA, sB, tab, t);
    float2* o = g_bufA + (size_t)row * 512;
    #pragma unroll
    for (int q = 0; q < 4; ++q) o[t + q * 128] = res[t + q * 128];
}

// ---------------------------------------------------------------------------
// transA: per-ca transpose (256 ym x 512 kx) -> (512 kx x 256 ym).
// ---------------------------------------------------------------------------
__global__ void k_transA() {
    __shared__ float2 tile[32][33];
    int ca = blockIdx.z;
    const float2* sIn = g_bufA + (size_t)ca * (256 * 512);
    float2* sOut = g_bufB + (size_t)ca * (512 * 256);
    int kx0 = blockIdx.x * 32, ym0 = blockIdx.y * 32;
    int tx = threadIdx.x, ty = threadIdx.y;
    for (int i = ty; i < 32; i += 8)
        tile[i][tx] = sIn[(size_t)(ym0 + i) * 512 + kx0 + tx];
    __syncthreads();
    for (int i = ty; i < 32; i += 8)
        sOut[(size_t)(kx0 + i) * 256 + ym0 + tx] = tile[tx][i];
}

// ---------------------------------------------------------------------------
// Column FFT with pad-on-load: block = ca*512 + kx; read the 256 band, pad
// to 512, forward FFT, write full 512 ky row into bufC.
// ---------------------------------------------------------------------------
__global__ void k_colfft() {
    int blk = blockIdx.x;            // ca*512 + kx
    int t = threadIdx.x;
    __shared__ float2 sA[512], sB[512], tab[256];
    build_tab128(tab, t);
    const float2* grow = g_bufB + (size_t)blk * 256;
    #pragma unroll
    for (int q = 0; q < 4; ++q) {
        int y = t + q * 128;
        sA[y] = (y >= 128 && y < 384) ? grow[y - 128] : make_float2(0.f, 0.f);
    }
    float2* res = fft512_tab<-1>(sA, sB, tab, t);
    float2* o = g_bufC + (size_t)blk * 512;
    #pragma unroll
    for (int q = 0; q < 4; ++q) o[t + q * 128] = res[t + q * 128];
}

// ---------------------------------------------------------------------------
// K-space mix (sum over ain, kernT pre-scaled) + column IFFT over ky, banded
// store. Block = (cl*A_+aout)*512 + kx.
// ---------------------------------------------------------------------------
__global__ void k_mixifft() {
    int blk = blockIdx.x;
    int ca = blk >> 9;               // cl*A_ + aout
    int kx = blk & 511;
    int cl = ca / A_;
    int aout = ca - cl * A_;
    int t = threadIdx.x;
    __shared__ float2 sA[512], sB[512], tab[256];
    build_tab128(tab, t);
    #pragma unroll
    for (int q = 0; q < 4; ++q) {
        int ky = t + q * 128;
        float2 acc = make_float2(0.f, 0.f);
        #pragma unroll
        for (int ain = 0; ain < A_; ++ain) {
            float2 kv = g_kernT[(((size_t)(aout * A_ + ain)) << 18) +
                                ((size_t)kx << 9) + ky];
            float2 fv = g_bufC[(((size_t)(cl * A_ + ain)) << 18) +
                               ((size_t)kx << 9) + ky];
            acc.x += kv.x * fv.x - kv.y * fv.y;
            acc.y += kv.x * fv.y + kv.y * fv.x;
        }
        sA[ky] = acc;
    }
    float2* res = fft512_tab<1>(sA, sB, tab, t);
    // keep y in [128,384) -> ym = y-128; store [ca][kx][ym]
    float2* o = g_bufA + (size_t)blk * 256;
    o[t]       = res[t + 128];
    o[t + 128] = res[t + 256];
}

// ---------------------------------------------------------------------------
// transB: per-ca transpose (512 kx x 256 ym) -> (256 ym x 512 kx).
// ---------------------------------------------------------------------------
__global__ void k_transB() {
    __shared__ float2 tile[32][33];
    int ca = blockIdx.z;
    const float2* sIn = g_bufA + (size_t)ca * (512 * 256);
    float2* sOut = g_bufB + (size_t)ca * (256 * 512);
    int ym0 = blockIdx.x * 32, kx0 = blockIdx.y * 32;
    int tx = threadIdx.x, ty = threadIdx.y;
    for (int i = ty; i < 32; i += 8)
        tile[i][tx] = sIn[(size_t)(kx0 + i) * 256 + ym0 + tx];
    __syncthreads();
    for (int i = ty; i < 32; i += 8)
        sOut[(size_t)(ym0 + i) * 512 + kx0 + tx] = tile[tx][i];
}

// ---------------------------------------------------------------------------
// Final stage, race-free group accumulation: block = (a, h) owns all CPG
// coils of the group — CPG sequential row IFFTs, conj(mps)*v accumulated in
// REGISTERS, then ONE plain write (+= for groups > 0) per output element.
// No atomics (R6/R7 crash suspect). Planar out: Re plane then Im plane.
// ---------------------------------------------------------------------------
__global__ void k_out_g(const float* __restrict__ mr, const float* __restrict__ mi,
                        int coilBase, int first, float* __restrict__ out,
                        int outFloats) {
    int row = blockIdx.x;            // a*256 + h
    int a = row >> 8;
    int h = row & 255;
    int t = threadIdx.x;
    __shared__ float2 sA[512], sB[512], tab[256];
    build_tab128(tab, t);
    float accr[2] = {0.f, 0.f}, acci[2] = {0.f, 0.f};
    for (int cl = 0; cl < CPG; ++cl) {
        const float2* s = g_bufB + (((size_t)(cl * A_ + a) * 256 + h)) * 512;
        #pragma unroll
        for (int q = 0; q < 4; ++q) sA[t + q * 128] = s[t + q * 128];
        // fft begins with __syncthreads() (covers the sA fill) and ends with
        // one (res=sB valid); next iteration overwrites sA only -> race-free.
        float2* res = fft512_tab<1>(sA, sB, tab, t);
        int coil = coilBase + cl;
        #pragma unroll
        for (int q = 0; q < 2; ++q) {
            int w = t + q * 128;
            float2 v = res[w + 128];
            size_t mIdx = ((size_t)coil * 256 + h) * 256 + w;
            float br = mr[mIdx], bi = -mi[mIdx];   // conj(mps)
            accr[q] += v.x * br - v.y * bi;
            acci[q] += v.x * bi + v.y * br;
        }
        __syncthreads();   // all res reads done before next iter's stage-0 writes to sB
    }
    #pragma unroll
    for (int q = 0; q < 2; ++q) {
        int w = t + q * 128;
        size_t p = ((size_t)a * 256 + h) * 256 + w;
        size_t reIdx = p, imIdx = 327680 + p;
        if (first) {
            if (reIdx < (size_t)outFloats) out[reIdx] = accr[q];
            if (imIdx < (size_t)outFloats) out[imIdx] = acci[q];
        } else {
            if (reIdx < (size_t)outFloats) out[reIdx] += accr[q];
            if (imIdx < (size_t)outFloats) out[imIdx] += acci[q];
        }
    }
}

// ---------------------------------------------------------------------------
extern "C" void kernel_launch(void* const* d_in, const int* in_sizes, int n_in,
                              void* d_out, int out_size, void* d_ws, size_t ws_size,
                              hipStream_t stream) {
    const float* xr = (const float*)d_in[0];
    const float* xi = (const float*)d_in[1];
    const float* mr = (const float*)d_in[2];
    const float* mi = (const float*)d_in[3];
    const float* kr = (const float*)d_in[4];
    const float* ki = (const float*)d_in[5];
    float* out = (float*)d_out;
    (void)d_ws; (void)ws_size; (void)n_in; (void)in_sizes;

    const float scale = 4.0f / 262144.0f;   // OVERSAMP^2/(Hp*Wp), ortho norms

    k_kernT2<<<dim3(16, 16, 25), dim3(32, 8), 0, stream>>>(kr, ki, scale);

    for (int g = 0; g < NG; ++g) {
        int cb = g * CPG;
        k_fft1c<<<RPG * 256, 128, 0, stream>>>(xr, xi, mr, mi, cb);
        k_transA<<<dim3(16, 8, RPG), dim3(32, 8), 0, stream>>>();
        k_colfft<<<RPG * 512, 128, 0, stream>>>();
        k_mixifft<<<RPG * 512, 128, 0, stream>>>();
        k_transB<<<dim3(8, 16, RPG), dim3(32, 8), 0, stream>>>();
        k_out_g<<<A_ * 256, 128, 0, stream>>>(mr, mi, cb, (g == 0) ? 1 : 0,
                                              out, out_size);
    }
}